// Round 12
// baseline (190.934 us; speedup 1.0000x reference)
//
#include <hip/hip_runtime.h>
#include <cstdint>
#include <cstddef>

#define IN_DIM 128
#define OUT_DIM 128
#define NR 8          // dst ranges == XCDs
#define NS 256        // nodes per sub-range
#define NSUB_MAX 64   // max sub-ranges per range (rs <= 16384)
#define LCAP 128      // LDS staging per sub per 4096-edge chunk (mean 10.4 in-range, +36 sigma)
#define SBCAP 4864    // records cap per sub-range bucket (mean 4082, +12 sigma)
#define SCAP 4864     // csr slab stride per sub-range

typedef int vint4 __attribute__((ext_vector_type(4)));
typedef float vfloat2 __attribute__((ext_vector_type(2)));
typedef short bf16x8 __attribute__((ext_vector_type(8)));   // 8 bf16 = 4 VGPRs (MFMA A/B frag)
typedef float f32x4 __attribute__((ext_vector_type(4)));    // MFMA C/D frag

// bf16 helpers (OCP bf16 = top 16 bits of fp32, RNE)
__device__ __forceinline__ unsigned short f2bf(float f) {
  unsigned int u = __float_as_uint(f);
  u = (u + 0x7FFFu + ((u >> 16) & 1u)) >> 16;
  return (unsigned short)u;
}
__device__ __forceinline__ float bf_lo(unsigned int v) { return __uint_as_float(v << 16); }
__device__ __forceinline__ float bf_hi(unsigned int v) { return __uint_as_float(v & 0xFFFF0000u); }

// ------------------------------------------------------------------ utils
__global__ void k_zero_i32(int* __restrict__ p, int n) {
  int i = blockIdx.x * blockDim.x + threadIdx.x;
  int st = gridDim.x * blockDim.x;
  for (; i < n; i += st) p[i] = 0;
}

__global__ void k_zero_f32(float* __restrict__ p, long long n) {
  long long i = (long long)blockIdx.x * blockDim.x + threadIdx.x;
  long long st = (long long)gridDim.x * blockDim.x;
  for (; i < n; i += st) p[i] = 0.0f;
}

// ------------------------------------------------------------------ merged init: zero meta + transpose W -> bf16 Wt_g[c][k]
__global__ void k_init(int* __restrict__ bmeta, int* __restrict__ sbcnt, int nB,
                       const float* __restrict__ W, unsigned short* __restrict__ Wt_g) {
  int gid = blockIdx.x * blockDim.x + threadIdx.x;
  int st = gridDim.x * blockDim.x;
  if (blockIdx.x == 0 && threadIdx.x < 16) bmeta[threadIdx.x] = 0;
  for (int i = gid; i < nB; i += st) sbcnt[i] = 0;
  for (int i = gid; i < IN_DIM * OUT_DIM; i += st) {
    int k = i >> 7, c = i & 127;           // coalesced read of W[k][c]
    Wt_g[c * IN_DIM + k] = f2bf(W[i]);     // scattered 2B write: 512KB sector traffic, trivial
  }
}

// ------------------------------------------------------------------ fallback-only: degree histogram + dinv
__global__ void k_hist(const int* __restrict__ dst, int E, int* __restrict__ deg) {
  int i = blockIdx.x * blockDim.x + threadIdx.x;
  int st = gridDim.x * blockDim.x;
  for (; i < E; i += st) atomicAdd(&deg[dst[i]], 1);
}

__global__ void k_dinv(const int* __restrict__ deg, float* __restrict__ dinv, int n) {
  int i = blockIdx.x * blockDim.x + threadIdx.x;
  int st = gridDim.x * blockDim.x;
  for (; i < n; i += st) dinv[i] = rsqrtf((float)(deg[i] + 1));
}

// ------------------------------------------------------------------ single-pass bucketing: edges -> per-sub-range buckets.
// Round-11 consolidation: replaces A1 (8-range bucket) + A2 (sub-bucket).
// Blocks with blockIdx&7==r handle range r (round-robin -> XCD r). Each
// range-group streams ALL edges (nt int4; 8x logical re-read but L3-resident
// after first touch), filters dst in range, stages per-sub in LDS (49 subs x
// LCAP, contention 1/6 of A1's 8-counter hammering), flushes dense spans into
// the sub-buckets subsort2 consumes. Kills the 6.4 MB intermediate bucket
// write+read and one launch. Zero scattered global atomics (r7 law:
// scattered atomic/4B-store = 32B fabric sector @ ~20 G/s).
__global__ __launch_bounds__(256) void k_bucket_direct(const int* __restrict__ ei, int E, int n,
                                                       unsigned int* __restrict__ sbkt,
                                                       int* __restrict__ sbcnt, int nsub,
                                                       int2* __restrict__ ovf, int* __restrict__ ocnt) {
  __shared__ unsigned int buf[NSUB_MAX][LCAP];  // 32 KB
  __shared__ int cnt[NSUB_MAX];
  __shared__ int base[NSUB_MAX];
  const int tid = threadIdx.x;
  const int r = blockIdx.x & 7;
  const int gblk = blockIdx.x >> 3;
  const int nblk = gridDim.x >> 3;
  const int rs = (n + NR - 1) / NR;
  const int lo = r * rs;
  const int hi = (lo + rs < n) ? lo + rs : n;
  const int E4 = E >> 2;
  const vint4* s4 = (const vint4*)ei;
  const vint4* d4 = (const vint4*)(ei + E);
  int nChunks = (E4 + 1023) >> 10;  // 1024 int4 = 4096 edges per chunk
  if (nChunks == 0) nChunks = 1;    // E < 4: tail-only

  for (int c = gblk; c < nChunks; c += nblk) {
    for (int t = tid; t < nsub; t += 256) cnt[t] = 0;
    __syncthreads();
    const int i0 = c << 10;
    const int iend = min(i0 + 1024, E4);
#define PUT(dd, ss)                                                                          \
    if ((dd) >= lo && (dd) < hi) {                                                           \
      int dl = (dd) - lo;                                                                    \
      int sb = dl >> 8;                                                                      \
      int pos = atomicAdd(&cnt[sb], 1);                                                      \
      if (pos < LCAP) buf[sb][pos] = ((unsigned int)dl << 17) | (unsigned int)(ss);          \
      else { int op = atomicAdd(ocnt, 1); ovf[op] = make_int2((ss), (dd)); }                 \
    }
    for (int i = i0 + tid; i < iend; i += 256) {
      vint4 s = __builtin_nontemporal_load(&s4[i]);
      vint4 d = __builtin_nontemporal_load(&d4[i]);
      PUT(d.x, s.x) PUT(d.y, s.y) PUT(d.z, s.z) PUT(d.w, s.w)
    }
    if (iend == E4) {  // this block owns the tail (E % 4 edges)
      for (int j = (E4 << 2) + tid; j < E; j += 256) {
        int ss = ei[j];
        int dd = ei[E + j];
        PUT(dd, ss)
      }
    }
#undef PUT
    __syncthreads();
    for (int t = tid; t < nsub; t += 256) {
      int m = cnt[t]; if (m > LCAP) m = LCAP;
      base[t] = m ? atomicAdd(&sbcnt[t * NR + r], m) : 0;
    }
    __syncthreads();
    for (int s2 = 0; s2 < nsub; ++s2) {
      int m = cnt[s2]; if (m > LCAP) m = LCAP;
      int b = base[s2];
      unsigned int* dp = sbkt + (size_t)(s2 * NR + r) * SBCAP;
      for (int j = tid; j < m; j += 256) {
        int idx = b + j;
        if (idx < SBCAP) __builtin_nontemporal_store(buf[s2][j], &dp[idx]);
        else {
          unsigned int w = buf[s2][j];
          int op = atomicAdd(ocnt, 1);
          ovf[op] = make_int2((int)(w & 0x1FFFFu), lo + (int)(w >> 17));
        }
      }
    }
    __syncthreads();
  }
}

// ------------------------------------------------------------------ phase B: per-sub-range LDS counting sort -> dense csr slabs.
__global__ __launch_bounds__(256) void k_subsort2(const unsigned int* __restrict__ sbkt,
                                                  const int* __restrict__ sbcnt, int n,
                                                  int* __restrict__ csr, int* __restrict__ rs_start,
                                                  int* __restrict__ cur_end, float* __restrict__ dinv) {
  __shared__ unsigned int raw[SBCAP];
  __shared__ unsigned int srt[SBCAP];
  __shared__ int hist[NS];
  __shared__ int pref[NS];
  __shared__ int off[NS];
  const int tid = threadIdx.x;
  const int r = blockIdx.x & 7;
  const int sub = blockIdx.x >> 3;
  const int rs = (n + NR - 1) / NR;
  const int rsz = min(rs, n - r * rs);
  const int lo_dl = sub << 8;
  if (lo_dl >= rsz) return;
  const int nsn = min(NS, rsz - lo_dl);

  hist[tid] = 0;
  __syncthreads();

  int m = sbcnt[blockIdx.x]; if (m > SBCAP) m = SBCAP;
  const unsigned int* bp = sbkt + (size_t)blockIdx.x * SBCAP;
  for (int i = tid; i < m; i += 256) {
    unsigned int w = bp[i];
    raw[i] = w;
    atomicAdd(&hist[(int)(w >> 17) & (NS - 1)], 1);
  }
  __syncthreads();

  pref[tid] = hist[tid];
  __syncthreads();
  for (int o = 1; o < NS; o <<= 1) {
    int v = pref[tid] + ((tid >= o) ? pref[tid - o] : 0);
    __syncthreads();
    pref[tid] = v;
    __syncthreads();
  }
  off[tid] = pref[tid] - hist[tid];
  __syncthreads();

  for (int i = tid; i < m; i += 256) {
    unsigned int w = raw[i];
    int p = atomicAdd(&off[(int)(w >> 17) & (NS - 1)], 1);
    srt[p] = w & 0x1FFFFu;
  }
  __syncthreads();

  const int sbase = blockIdx.x * SCAP;
  for (int i = tid; i < m; i += 256) csr[sbase + i] = (int)srt[i];
  if (tid < nsn) {
    int node = r * rs + lo_dl + tid;
    rs_start[node] = sbase + pref[tid] - hist[tid];
    cur_end[node] = sbase + pref[tid];
    dinv[node] = rsqrtf((float)(hist[tid] + 1));  // +1 self-loop
  }
}

// ------------------------------------------------------------------ overflow net (statistically never populated)
__global__ void k_scatter_ovf(const int2* __restrict__ ovf, const int* __restrict__ ocnt,
                              int* __restrict__ cur_end, int* __restrict__ csr, int csr_total) {
  int m = *ocnt;
  for (int i = blockIdx.x * blockDim.x + threadIdx.x; i < m; i += gridDim.x * blockDim.x) {
    int2 e = ovf[i];
    int p = atomicAdd(&cur_end[e.y], 1);
    if (p >= 0 && p < csr_total) csr[p] = e.x;
  }
}

// ------------------------------------------------------------------ MFMA GEMM: gb = bf16((x @ W) * dinv[row])
__global__ __launch_bounds__(256) void k_gemm_mfma(const float* __restrict__ x,
                                                   const unsigned short* __restrict__ Wt_g,
                                                   const float* __restrict__ dinv,
                                                   unsigned short* __restrict__ gb, int M) {
  __shared__ unsigned short xT[64][136];   // [row][k] bf16, 17.0 KB
  __shared__ unsigned short Wt[128][136];  // [col][k] bf16, 34.0 KB
  const int tid = threadIdx.x;
  const int row0 = blockIdx.x * 64;

  for (int i = tid; i < (IN_DIM * OUT_DIM) / 8; i += 256) {
    int c = i >> 4, k8 = (i & 15) * 8;
    uint4 v = *(const uint4*)(Wt_g + (size_t)c * IN_DIM + k8);
    *(uint4*)&Wt[c][k8] = v;
  }
  for (int i = tid; i < (64 * IN_DIM) / 4; i += 256) {
    int idx = i * 4;
    int r = idx >> 7, k = idx & 127;
    int grow = row0 + r; if (grow >= M) grow = M - 1;
    float4 v = *(const float4*)(x + (size_t)grow * IN_DIM + k);
    ushort4 b;
    b.x = f2bf(v.x); b.y = f2bf(v.y); b.z = f2bf(v.z); b.w = f2bf(v.w);
    *(ushort4*)&xT[r][k] = b;
  }
  __syncthreads();

  const int wv = tid >> 6;
  const int lane = tid & 63;
  const int l15 = lane & 15;
  const int lk8 = (lane >> 4) * 8;

  f32x4 acc[8];
#pragma unroll
  for (int ct = 0; ct < 8; ++ct) acc[ct] = (f32x4){0.f, 0.f, 0.f, 0.f};

#pragma unroll
  for (int kt = 0; kt < 4; ++kt) {
    bf16x8 a = *(const bf16x8*)&xT[wv * 16 + l15][kt * 32 + lk8];
#pragma unroll
    for (int ct = 0; ct < 8; ++ct) {
      bf16x8 b = *(const bf16x8*)&Wt[ct * 16 + l15][kt * 32 + lk8];
      acc[ct] = __builtin_amdgcn_mfma_f32_16x16x32_bf16(a, b, acc[ct], 0, 0, 0);
    }
  }

  const int drow0 = wv * 16 + (lane >> 4) * 4;
#pragma unroll
  for (int reg = 0; reg < 4; ++reg) {
    int grow = row0 + drow0 + reg;
    if (grow < M) {
      float s = dinv[grow];
      unsigned short* gp = gb + (size_t)grow * OUT_DIM + l15;
#pragma unroll
      for (int ct = 0; ct < 8; ++ct) {
        gp[ct * 16] = f2bf(acc[ct][reg] * s);
      }
    }
  }
}

// ------------------------------------------------------------------ fallback fp32 GEMM (non-bucketed path)
__global__ __launch_bounds__(256) void k_gemm_scale(const float* __restrict__ x, const float* __restrict__ W,
                                                    const float* __restrict__ dinv,
                                                    unsigned short* __restrict__ gb, int M) {
  __shared__ float xT[32][128];
  __shared__ float Ws[32][128];
  const int tid = threadIdx.x;
  const int tc = tid & 15;
  const int tr = tid >> 4;
  const int row0 = blockIdx.x * 128;
  const int lr = tid & 127;
  const int lk = (tid >> 7) * 16;

  float acc[8][8] = {};

  for (int k0 = 0; k0 < IN_DIM; k0 += 32) {
    int grow = row0 + lr;
    if (grow >= M) grow = M - 1;
    const float4* xp = (const float4*)(x + (size_t)grow * IN_DIM + k0 + lk);
    float4 a0 = xp[0], a1 = xp[1], a2 = xp[2], a3 = xp[3];
    const float4* wp = (const float4*)(W + (size_t)(k0 + (tid >> 3)) * OUT_DIM + (tid & 7) * 16);
    float4 w0 = wp[0], w1 = wp[1], w2 = wp[2], w3 = wp[3];

    __syncthreads();
    xT[lk + 0][lr] = a0.x;  xT[lk + 1][lr] = a0.y;  xT[lk + 2][lr] = a0.z;  xT[lk + 3][lr] = a0.w;
    xT[lk + 4][lr] = a1.x;  xT[lk + 5][lr] = a1.y;  xT[lk + 6][lr] = a1.z;  xT[lk + 7][lr] = a1.w;
    xT[lk + 8][lr] = a2.x;  xT[lk + 9][lr] = a2.y;  xT[lk + 10][lr] = a2.z; xT[lk + 11][lr] = a2.w;
    xT[lk + 12][lr] = a3.x; xT[lk + 13][lr] = a3.y; xT[lk + 14][lr] = a3.z; xT[lk + 15][lr] = a3.w;
    float4* wsp = (float4*)&Ws[tid >> 3][(tid & 7) * 16];
    wsp[0] = w0; wsp[1] = w1; wsp[2] = w2; wsp[3] = w3;
    __syncthreads();

#pragma unroll
    for (int k = 0; k < 32; ++k) {
      float xv[8], wvv[8];
      *(float4*)&xv[0] = *(const float4*)&xT[k][tr * 8];
      *(float4*)&xv[4] = *(const float4*)&xT[k][tr * 8 + 4];
      *(float4*)&wvv[0] = *(const float4*)&Ws[k][tc * 8];
      *(float4*)&wvv[4] = *(const float4*)&Ws[k][tc * 8 + 4];
#pragma unroll
      for (int ii = 0; ii < 8; ++ii)
#pragma unroll
        for (int jj = 0; jj < 8; ++jj)
          acc[ii][jj] = fmaf(xv[ii], wvv[jj], acc[ii][jj]);
    }
  }

#pragma unroll
  for (int ii = 0; ii < 8; ++ii) {
    int rr = row0 + tr * 8 + ii;
    if (rr < M) {
      float s = dinv[rr];
      uint4 o;
      o.x = (unsigned int)f2bf(acc[ii][0] * s) | ((unsigned int)f2bf(acc[ii][1] * s) << 16);
      o.y = (unsigned int)f2bf(acc[ii][2] * s) | ((unsigned int)f2bf(acc[ii][3] * s) << 16);
      o.z = (unsigned int)f2bf(acc[ii][4] * s) | ((unsigned int)f2bf(acc[ii][5] * s) << 16);
      o.w = (unsigned int)f2bf(acc[ii][6] * s) | ((unsigned int)f2bf(acc[ii][7] * s) << 16);
      *(uint4*)(gb + (size_t)rr * OUT_DIM + tc * 8) = o;
    }
  }
}

// ------------------------------------------------------------------ pull aggregation over [rs_start, cur_end) slabs (full-width,
// round-10 form restored — r11's column-split regressed: fabric is
// transaction-limited, halving bytes/gather doubled transactions).
__global__ __launch_bounds__(256) void k_agg_se(const unsigned short* __restrict__ gb,
                                                const int* __restrict__ rs_start, const int* __restrict__ cur_end,
                                                const int* __restrict__ csr, const float* __restrict__ dinv,
                                                const float* __restrict__ bias, float* __restrict__ out, int n) {
  const int lane = threadIdx.x & 63;
  const int wave = __builtin_amdgcn_readfirstlane(threadIdx.x >> 6);
  const int wpb = blockDim.x >> 6;
  const int nWaves = gridDim.x * wpb;
  const int c2 = lane * 2;
  const float2 bb = *(const float2*)(bias + c2);

  for (int node = blockIdx.x * wpb + wave; node < n; node += nWaves) {
    const int s = rs_start[node];
    const int e = cur_end[node];
    unsigned int sv = *(const unsigned int*)(gb + (size_t)node * OUT_DIM + c2);
    float ax = bf_lo(sv), ay = bf_hi(sv);
    int i = s;
    for (; i + 8 <= e; i += 8) {
      int s0 = csr[i + 0], s1 = csr[i + 1], s2 = csr[i + 2], s3 = csr[i + 3];
      int s4 = csr[i + 4], s5 = csr[i + 5], s6 = csr[i + 6], s7 = csr[i + 7];
      unsigned int v0 = *(const unsigned int*)(gb + (size_t)s0 * OUT_DIM + c2);
      unsigned int v1 = *(const unsigned int*)(gb + (size_t)s1 * OUT_DIM + c2);
      unsigned int v2 = *(const unsigned int*)(gb + (size_t)s2 * OUT_DIM + c2);
      unsigned int v3 = *(const unsigned int*)(gb + (size_t)s3 * OUT_DIM + c2);
      unsigned int v4 = *(const unsigned int*)(gb + (size_t)s4 * OUT_DIM + c2);
      unsigned int v5 = *(const unsigned int*)(gb + (size_t)s5 * OUT_DIM + c2);
      unsigned int v6 = *(const unsigned int*)(gb + (size_t)s6 * OUT_DIM + c2);
      unsigned int v7 = *(const unsigned int*)(gb + (size_t)s7 * OUT_DIM + c2);
      ax += ((bf_lo(v0) + bf_lo(v1)) + (bf_lo(v2) + bf_lo(v3))) +
            ((bf_lo(v4) + bf_lo(v5)) + (bf_lo(v6) + bf_lo(v7)));
      ay += ((bf_hi(v0) + bf_hi(v1)) + (bf_hi(v2) + bf_hi(v3))) +
            ((bf_hi(v4) + bf_hi(v5)) + (bf_hi(v6) + bf_hi(v7)));
    }
    for (; i < e; ++i) {
      unsigned int v = *(const unsigned int*)(gb + (size_t)csr[i] * OUT_DIM + c2);
      ax += bf_lo(v);
      ay += bf_hi(v);
    }
    const float di = dinv[node];
    vfloat2 o;
    o.x = fmaxf(fmaf(ax, di, bb.x), 0.0f);
    o.y = fmaxf(fmaf(ay, di, bb.y), 0.0f);
    __builtin_nontemporal_store(o, (vfloat2*)(out + (size_t)node * OUT_DIM + c2));
  }
}

// ------------------------------------------------------------------ fallback (small ws): atomic scatter
__global__ __launch_bounds__(256) void k_scatter(const int* __restrict__ ei, int E,
                                                 const unsigned short* __restrict__ gb, float* __restrict__ out) {
  const int lane = threadIdx.x & 63;
  const int wave = __builtin_amdgcn_readfirstlane(threadIdx.x >> 6);
  const int wpb = blockDim.x >> 6;
  const int nWaves = gridDim.x * wpb;
  const int c2 = lane * 2;
  for (int e = blockIdx.x * wpb + wave; e < E; e += nWaves) {
    int s = ei[e];
    int d = ei[E + e];
    unsigned int v = *(const unsigned int*)(gb + (size_t)s * OUT_DIM + c2);
    atomicAdd(&out[(size_t)d * OUT_DIM + c2 + 0], bf_lo(v));
    atomicAdd(&out[(size_t)d * OUT_DIM + c2 + 1], bf_hi(v));
  }
}

__global__ void k_finalize(const unsigned short* __restrict__ gb, const float* __restrict__ dinv,
                           const float* __restrict__ bias, float* __restrict__ out, int n) {
  int i = blockIdx.x * blockDim.x + threadIdx.x;
  int st = gridDim.x * blockDim.x;
  int total = n * OUT_DIM;
  for (; i < total; i += st) {
    int node = i >> 7;
    float gv = __uint_as_float(((unsigned int)gb[i]) << 16);
    float v = (out[i] + gv) * dinv[node] + bias[i & 127];
    out[i] = fmaxf(v, 0.0f);
  }
}

// ------------------------------------------------------------------ launch
extern "C" void kernel_launch(void* const* d_in, const int* in_sizes, int n_in,
                              void* d_out, int out_size, void* d_ws, size_t ws_size,
                              hipStream_t stream) {
  const float* x = (const float*)d_in[0];
  const int* ei = (const int*)d_in[1];   // int64 in reference -> delivered as int32
  const float* W = (const float*)d_in[2];
  const float* bias = (const float*)d_in[3];
  float* out = (float*)d_out;

  const int N = in_sizes[0] / IN_DIM;  // 100000
  const int E = in_sizes[1] / 2;       // 1600000

  const int rs = (N + NR - 1) / NR;
  const int nsub = (rs + NS - 1) / NS;         // 49
  const int nBlocksB = nsub * NR;              // 392
  const int csr_total = nBlocksB * SCAP;
  const int mBlocks64 = (N + 63) / 64;

  char* ws = (char*)d_ws;
  size_t off = 0;
  auto alloc = [&](size_t bytes) -> void* {
    void* p = ws + off;
    off += (bytes + 255) & ~(size_t)255;
    return p;
  };

  unsigned short* gb = (unsigned short*)alloc((size_t)N * OUT_DIM * sizeof(unsigned short));  // 25.6 MB
  float* dinv = (float*)alloc((size_t)N * sizeof(float));
  int* rs_start = (int*)alloc((size_t)N * sizeof(int));
  int* cur_end = (int*)alloc((size_t)N * sizeof(int));
  int* csr = (int*)alloc((size_t)csr_total * sizeof(int));                                    // 7.6 MB
  unsigned int* sbkt = (unsigned int*)alloc((size_t)nBlocksB * SBCAP * sizeof(unsigned int)); // 7.6 MB
  int* sbcnt = (int*)alloc((size_t)nBlocksB * sizeof(int));
  unsigned short* Wt_g = (unsigned short*)alloc((size_t)IN_DIM * OUT_DIM * sizeof(unsigned short));  // 32 KB
  int* bmeta = (int*)alloc(16 * sizeof(int));
  int2* ovf = (int2*)alloc((size_t)(E / 8 + 1024) * sizeof(int2));                            // 1.6 MB
  size_t bucket_need = off;

  const bool bucketed = (ws_size >= bucket_need) && (N <= (1 << 17)) && (rs <= (1 << 14)) &&
                        (nsub <= NSUB_MAX) && ((E & 3) == 0 || E < 4);

  if (bucketed) {
    k_init<<<64, 256, 0, stream>>>(bmeta, sbcnt, nBlocksB, W, Wt_g);
    k_bucket_direct<<<2048, 256, 0, stream>>>(ei, E, N, sbkt, sbcnt, nsub, ovf, bmeta + 8);
    k_subsort2<<<nBlocksB, 256, 0, stream>>>(sbkt, sbcnt, N, csr, rs_start, cur_end, dinv);
    k_gemm_mfma<<<mBlocks64, 256, 0, stream>>>(x, Wt_g, dinv, gb, N);
    k_scatter_ovf<<<64, 256, 0, stream>>>(ovf, bmeta + 8, cur_end, csr, csr_total);
    k_agg_se<<<2048, 256, 0, stream>>>(gb, rs_start, cur_end, csr, dinv, bias, out, N);
  } else {
    off = 0;
    unsigned short* gb2 = (unsigned short*)alloc((size_t)N * OUT_DIM * sizeof(unsigned short));
    int* deg = (int*)alloc((size_t)N * sizeof(int));
    float* dinv2 = (float*)alloc((size_t)N * sizeof(float));
    if (ws_size < off) return;
    k_zero_i32<<<256, 256, 0, stream>>>(deg, N);
    k_hist<<<2048, 256, 0, stream>>>(ei + E, E, deg);
    k_dinv<<<512, 256, 0, stream>>>(deg, dinv2, N);
    k_gemm_scale<<<(N + 127) / 128, 256, 0, stream>>>(x, W, dinv2, gb2, N);
    k_zero_f32<<<2048, 256, 0, stream>>>(out, (long long)N * OUT_DIM);
    k_scatter<<<4096, 256, 0, stream>>>(ei, E, gb2, out);
    k_finalize<<<2048, 256, 0, stream>>>(gb2, dinv2, bias, out, N);
  }
}

// Round 13
// 151.823 us; speedup vs baseline: 1.2576x; 1.2576x over previous
//
#include <hip/hip_runtime.h>
#include <cstdint>
#include <cstddef>

#define IN_DIM 128
#define OUT_DIM 128
#define NR 8          // dst ranges == XCDs
#define ACAP 448      // phase-A1 LDS staging per 2048-edge chunk per range
#define NS 256        // nodes per sub-range
#define NSUB_MAX 64   // max sub-ranges per range (rs <= 16384)
#define LCAP 192      // phase-A2 LDS staging per sub per 4096-record chunk
#define SBCAP 4864    // records cap per sub-range bucket (mean 4082, +12 sigma)
#define SCAP 4864     // csr slab stride per sub-range

typedef int vint4 __attribute__((ext_vector_type(4)));
typedef float vfloat2 __attribute__((ext_vector_type(2)));
typedef short bf16x8 __attribute__((ext_vector_type(8)));   // 8 bf16 = 4 VGPRs (MFMA A/B frag)
typedef float f32x4 __attribute__((ext_vector_type(4)));    // MFMA C/D frag

// bf16 helpers (OCP bf16 = top 16 bits of fp32, RNE)
__device__ __forceinline__ unsigned short f2bf(float f) {
  unsigned int u = __float_as_uint(f);
  u = (u + 0x7FFFu + ((u >> 16) & 1u)) >> 16;
  return (unsigned short)u;
}
__device__ __forceinline__ float bf_lo(unsigned int v) { return __uint_as_float(v << 16); }
__device__ __forceinline__ float bf_hi(unsigned int v) { return __uint_as_float(v & 0xFFFF0000u); }

// ------------------------------------------------------------------ utils
__global__ void k_zero_i32(int* __restrict__ p, int n) {
  int i = blockIdx.x * blockDim.x + threadIdx.x;
  int st = gridDim.x * blockDim.x;
  for (; i < n; i += st) p[i] = 0;
}

__global__ void k_zero_f32(float* __restrict__ p, long long n) {
  long long i = (long long)blockIdx.x * blockDim.x + threadIdx.x;
  long long st = (long long)gridDim.x * blockDim.x;
  for (; i < n; i += st) p[i] = 0.0f;
}

// ------------------------------------------------------------------ merged init: zero meta + transpose W -> bf16 Wt_g[c][k]
__global__ void k_init(int* __restrict__ bmeta, int* __restrict__ sbcnt, int nB,
                       const float* __restrict__ W, unsigned short* __restrict__ Wt_g) {
  int gid = blockIdx.x * blockDim.x + threadIdx.x;
  int st = gridDim.x * blockDim.x;
  if (blockIdx.x == 0 && threadIdx.x < 16) bmeta[threadIdx.x] = 0;
  for (int i = gid; i < nB; i += st) sbcnt[i] = 0;
  for (int i = gid; i < IN_DIM * OUT_DIM; i += st) {
    int k = i >> 7, c = i & 127;           // coalesced read of W[k][c]
    Wt_g[c * IN_DIM + k] = f2bf(W[i]);     // scattered 2B write: 512KB sector traffic, trivial
  }
}

// ------------------------------------------------------------------ fallback-only: degree histogram + dinv
__global__ void k_hist(const int* __restrict__ dst, int E, int* __restrict__ deg) {
  int i = blockIdx.x * blockDim.x + threadIdx.x;
  int st = gridDim.x * blockDim.x;
  for (; i < E; i += st) atomicAdd(&deg[dst[i]], 1);
}

__global__ void k_dinv(const int* __restrict__ deg, float* __restrict__ dinv, int n) {
  int i = blockIdx.x * blockDim.x + threadIdx.x;
  int st = gridDim.x * blockDim.x;
  for (; i < n; i += st) dinv[i] = rsqrtf((float)(deg[i] + 1));
}

// ------------------------------------------------------------------ phase A1: bucket edges by dst-range (XCD). No scattered atomics.
// (r12 falsified the merged single-pass variant: 8x re-stream ran at 880 GB/s
// latency-bound with 35% occupancy -> 80 us. Two-level with dense handoff wins.)
__global__ __launch_bounds__(256) void k_bucket2(const int* __restrict__ ei, int E, int n,
                                                 unsigned int* __restrict__ bkt, int bcap,
                                                 int* __restrict__ bcnt,
                                                 int2* __restrict__ ovf, int* __restrict__ ocnt) {
  __shared__ unsigned int buf[NR][ACAP];
  __shared__ int cnt[NR];
  __shared__ int base[NR];
  const int rs = (n + NR - 1) / NR;
  const int tid = threadIdx.x;
  const int E4 = E >> 2;
  const vint4* s4 = (const vint4*)ei;
  const vint4* d4 = (const vint4*)(ei + E);
  const int nChunks = (E4 + 511) >> 9;  // 512 int4 = 2048 edges per chunk

  for (int c = blockIdx.x; c < nChunks; c += gridDim.x) {
    if (tid < NR) cnt[tid] = 0;
    __syncthreads();
    const int i0 = c << 9;
#pragma unroll
    for (int u = 0; u < 2; ++u) {
      int i = i0 + (u << 8) + tid;
      if (i < E4) {
        vint4 s = __builtin_nontemporal_load(&s4[i]);
        vint4 d = __builtin_nontemporal_load(&d4[i]);
#define PUT(dd, ss)                                                                         \
        {                                                                                   \
          int rr = (dd) / rs;                                                               \
          unsigned int w = ((unsigned int)((dd) - rr * rs) << 17) | (unsigned int)(ss);     \
          int pos = atomicAdd(&cnt[rr], 1);                                                 \
          if (pos < ACAP) buf[rr][pos] = w;                                                 \
          else { int op = atomicAdd(ocnt, 1); ovf[op] = make_int2((ss), (dd)); }            \
        }
        PUT(d.x, s.x) PUT(d.y, s.y) PUT(d.z, s.z) PUT(d.w, s.w)
#undef PUT
      }
    }
    __syncthreads();
    if (tid < NR) {
      int m = cnt[tid]; if (m > ACAP) m = ACAP;
      base[tid] = atomicAdd(&bcnt[tid], m);
    }
    __syncthreads();
#pragma unroll
    for (int r = 0; r < NR; ++r) {
      int m = cnt[r]; if (m > ACAP) m = ACAP;
      int b = base[r];
      unsigned int* dp = bkt + (size_t)r * bcap;
      for (int j = tid; j < m; j += 256) {
        int idx = b + j;
        if (idx < bcap) __builtin_nontemporal_store(buf[r][j], &dp[idx]);
        else {
          unsigned int w = buf[r][j];
          int op = atomicAdd(ocnt, 1);
          ovf[op] = make_int2((int)(w & 0x1FFFFu), r * rs + (int)(w >> 17));
        }
      }
    }
    __syncthreads();
  }
  if (blockIdx.x == 0 && tid == 0) {  // tail edges (E % 4)
    for (int i = E4 << 2; i < E; ++i) {
      int s = ei[i], d = ei[E + i];
      int r = d / rs;
      int p = atomicAdd(&bcnt[r], 1);
      if (p < bcap) bkt[(size_t)r * bcap + p] = ((unsigned int)(d - r * rs) << 17) | (unsigned int)s;
      else { int op = atomicAdd(ocnt, 1); ovf[op] = make_int2(s, d); }
    }
  }
}

// ------------------------------------------------------------------ phase A2: re-bucket each XCD range into per-sub-range buckets.
__global__ __launch_bounds__(256) void k_subbkt(const unsigned int* __restrict__ bkt, int bcap,
                                                const int* __restrict__ bcnt,
                                                unsigned int* __restrict__ sbkt,
                                                int* __restrict__ sbcnt, int nsub, int n,
                                                int2* __restrict__ ovf, int* __restrict__ ocnt) {
  __shared__ unsigned int buf[NSUB_MAX][LCAP];  // 48 KB
  __shared__ int cnt[NSUB_MAX];
  __shared__ int base[NSUB_MAX];
  const int tid = threadIdx.x;
  const int r = blockIdx.x & 7;
  const int gblk = blockIdx.x >> 3;
  const int nblk = gridDim.x >> 3;
  const int rs = (n + NR - 1) / NR;
  int cr = bcnt[r]; if (cr > bcap) cr = bcap;
  const unsigned int* bp = bkt + (size_t)r * bcap;
  const int nChunks = (cr + 4095) >> 12;

  for (int c = gblk; c < nChunks; c += nblk) {
    for (int t = tid; t < nsub; t += 256) cnt[t] = 0;
    __syncthreads();
    const int i0 = c << 12;
    const int iend = min(i0 + 4096, cr);
    for (int i = i0 + tid; i < iend; i += 256) {
      unsigned int w = bp[i];
      int sub = (int)(w >> 25);
      int pos = atomicAdd(&cnt[sub], 1);
      if (pos < LCAP) buf[sub][pos] = w;
      else { int op = atomicAdd(ocnt, 1); ovf[op] = make_int2((int)(w & 0x1FFFFu), r * rs + (int)(w >> 17)); }
    }
    __syncthreads();
    for (int t = tid; t < nsub; t += 256) {
      int m = cnt[t]; if (m > LCAP) m = LCAP;
      base[t] = atomicAdd(&sbcnt[t * NR + r], m);
    }
    __syncthreads();
    for (int s = 0; s < nsub; ++s) {
      int m = cnt[s]; if (m > LCAP) m = LCAP;
      int b = base[s];
      unsigned int* dp = sbkt + (size_t)(s * NR + r) * SBCAP;
      for (int j = tid; j < m; j += 256) {
        int idx = b + j;
        if (idx < SBCAP) dp[idx] = buf[s][j];
        else {
          unsigned int w = buf[s][j];
          int op = atomicAdd(ocnt, 1);
          ovf[op] = make_int2((int)(w & 0x1FFFFu), r * rs + (int)(w >> 17));
        }
      }
    }
    __syncthreads();
  }
}

// ------------------------------------------------------------------ phase B: per-sub-range LDS counting sort -> dense csr slabs.
// Now ALSO absorbs the overflow net: ovf is complete before this launch
// (producers are A1/A2), so each block scans the (statistically empty) ovf
// list for its sub-range and appends before the histogram/sort. Removes the
// k_scatter_ovf launch and fixes the latent dinv-excludes-ovf bug.
__global__ __launch_bounds__(256) void k_subsort2(const unsigned int* __restrict__ sbkt,
                                                  const int* __restrict__ sbcnt, int n,
                                                  int* __restrict__ csr, int* __restrict__ rs_start,
                                                  int* __restrict__ cur_end, float* __restrict__ dinv,
                                                  const int2* __restrict__ ovf, const int* __restrict__ ocnt) {
  __shared__ unsigned int raw[SBCAP];
  __shared__ unsigned int srt[SBCAP];
  __shared__ int hist[NS];
  __shared__ int pref[NS];
  __shared__ int off[NS];
  __shared__ int xm;
  const int tid = threadIdx.x;
  const int r = blockIdx.x & 7;
  const int sub = blockIdx.x >> 3;
  const int rs = (n + NR - 1) / NR;
  const int rsz = min(rs, n - r * rs);
  const int lo_dl = sub << 8;
  if (lo_dl >= rsz) return;
  const int nsn = min(NS, rsz - lo_dl);

  hist[tid] = 0;
  __syncthreads();

  int m = sbcnt[blockIdx.x]; if (m > SBCAP) m = SBCAP;
  if (tid == 0) xm = m;
  const unsigned int* bp = sbkt + (size_t)blockIdx.x * SBCAP;
  for (int i = tid; i < m; i += 256) {
    unsigned int w = bp[i];
    raw[i] = w;
    atomicAdd(&hist[(int)(w >> 17) & (NS - 1)], 1);
  }
  __syncthreads();

  // absorb overflow records belonging to this sub-range (normally 0 iters)
  int om = *ocnt;
  for (int i = tid; i < om; i += 256) {
    int2 e = ovf[i];
    int dl = e.y - r * rs;
    if (dl >= lo_dl && dl < lo_dl + nsn) {
      int p = atomicAdd(&xm, 1);
      if (p < SBCAP) {
        unsigned int w = ((unsigned int)dl << 17) | (unsigned int)e.x;
        raw[p] = w;
        atomicAdd(&hist[dl & (NS - 1)], 1);
      }
    }
  }
  __syncthreads();
  m = min(xm, SBCAP);

  pref[tid] = hist[tid];
  __syncthreads();
  for (int o = 1; o < NS; o <<= 1) {
    int v = pref[tid] + ((tid >= o) ? pref[tid - o] : 0);
    __syncthreads();
    pref[tid] = v;
    __syncthreads();
  }
  off[tid] = pref[tid] - hist[tid];
  __syncthreads();

  for (int i = tid; i < m; i += 256) {
    unsigned int w = raw[i];
    int p = atomicAdd(&off[(int)(w >> 17) & (NS - 1)], 1);
    srt[p] = w & 0x1FFFFu;
  }
  __syncthreads();

  const int sbase = blockIdx.x * SCAP;
  for (int i = tid; i < m; i += 256) csr[sbase + i] = (int)srt[i];
  if (tid < nsn) {
    int node = r * rs + lo_dl + tid;
    rs_start[node] = sbase + pref[tid] - hist[tid];
    cur_end[node] = sbase + pref[tid];
    dinv[node] = rsqrtf((float)(hist[tid] + 1));  // +1 self-loop
  }
}

// ------------------------------------------------------------------ MFMA GEMM: gb = bf16((x @ W) * dinv[row])
__global__ __launch_bounds__(256) void k_gemm_mfma(const float* __restrict__ x,
                                                   const unsigned short* __restrict__ Wt_g,
                                                   const float* __restrict__ dinv,
                                                   unsigned short* __restrict__ gb, int M) {
  __shared__ unsigned short xT[64][136];   // [row][k] bf16, 17.0 KB
  __shared__ unsigned short Wt[128][136];  // [col][k] bf16, 34.0 KB
  const int tid = threadIdx.x;
  const int row0 = blockIdx.x * 64;

  for (int i = tid; i < (IN_DIM * OUT_DIM) / 8; i += 256) {
    int c = i >> 4, k8 = (i & 15) * 8;
    uint4 v = *(const uint4*)(Wt_g + (size_t)c * IN_DIM + k8);
    *(uint4*)&Wt[c][k8] = v;
  }
  for (int i = tid; i < (64 * IN_DIM) / 4; i += 256) {
    int idx = i * 4;
    int r = idx >> 7, k = idx & 127;
    int grow = row0 + r; if (grow >= M) grow = M - 1;
    float4 v = *(const float4*)(x + (size_t)grow * IN_DIM + k);
    ushort4 b;
    b.x = f2bf(v.x); b.y = f2bf(v.y); b.z = f2bf(v.z); b.w = f2bf(v.w);
    *(ushort4*)&xT[r][k] = b;
  }
  __syncthreads();

  const int wv = tid >> 6;
  const int lane = tid & 63;
  const int l15 = lane & 15;
  const int lk8 = (lane >> 4) * 8;

  f32x4 acc[8];
#pragma unroll
  for (int ct = 0; ct < 8; ++ct) acc[ct] = (f32x4){0.f, 0.f, 0.f, 0.f};

#pragma unroll
  for (int kt = 0; kt < 4; ++kt) {
    bf16x8 a = *(const bf16x8*)&xT[wv * 16 + l15][kt * 32 + lk8];
#pragma unroll
    for (int ct = 0; ct < 8; ++ct) {
      bf16x8 b = *(const bf16x8*)&Wt[ct * 16 + l15][kt * 32 + lk8];
      acc[ct] = __builtin_amdgcn_mfma_f32_16x16x32_bf16(a, b, acc[ct], 0, 0, 0);
    }
  }

  const int drow0 = wv * 16 + (lane >> 4) * 4;
#pragma unroll
  for (int reg = 0; reg < 4; ++reg) {
    int grow = row0 + drow0 + reg;
    if (grow < M) {
      float s = dinv[grow];
      unsigned short* gp = gb + (size_t)grow * OUT_DIM + l15;
#pragma unroll
      for (int ct = 0; ct < 8; ++ct) {
        gp[ct * 16] = f2bf(acc[ct][reg] * s);
      }
    }
  }
}

// ------------------------------------------------------------------ fallback fp32 GEMM (non-bucketed path)
__global__ __launch_bounds__(256) void k_gemm_scale(const float* __restrict__ x, const float* __restrict__ W,
                                                    const float* __restrict__ dinv,
                                                    unsigned short* __restrict__ gb, int M) {
  __shared__ float xT[32][128];
  __shared__ float Ws[32][128];
  const int tid = threadIdx.x;
  const int tc = tid & 15;
  const int tr = tid >> 4;
  const int row0 = blockIdx.x * 128;
  const int lr = tid & 127;
  const int lk = (tid >> 7) * 16;

  float acc[8][8] = {};

  for (int k0 = 0; k0 < IN_DIM; k0 += 32) {
    int grow = row0 + lr;
    if (grow >= M) grow = M - 1;
    const float4* xp = (const float4*)(x + (size_t)grow * IN_DIM + k0 + lk);
    float4 a0 = xp[0], a1 = xp[1], a2 = xp[2], a3 = xp[3];
    const float4* wp = (const float4*)(W + (size_t)(k0 + (tid >> 3)) * OUT_DIM + (tid & 7) * 16);
    float4 w0 = wp[0], w1 = wp[1], w2 = wp[2], w3 = wp[3];

    __syncthreads();
    xT[lk + 0][lr] = a0.x;  xT[lk + 1][lr] = a0.y;  xT[lk + 2][lr] = a0.z;  xT[lk + 3][lr] = a0.w;
    xT[lk + 4][lr] = a1.x;  xT[lk + 5][lr] = a1.y;  xT[lk + 6][lr] = a1.z;  xT[lk + 7][lr] = a1.w;
    xT[lk + 8][lr] = a2.x;  xT[lk + 9][lr] = a2.y;  xT[lk + 10][lr] = a2.z; xT[lk + 11][lr] = a2.w;
    xT[lk + 12][lr] = a3.x; xT[lk + 13][lr] = a3.y; xT[lk + 14][lr] = a3.z; xT[lk + 15][lr] = a3.w;
    float4* wsp = (float4*)&Ws[tid >> 3][(tid & 7) * 16];
    wsp[0] = w0; wsp[1] = w1; wsp[2] = w2; wsp[3] = w3;
    __syncthreads();

#pragma unroll
    for (int k = 0; k < 32; ++k) {
      float xv[8], wvv[8];
      *(float4*)&xv[0] = *(const float4*)&xT[k][tr * 8];
      *(float4*)&xv[4] = *(const float4*)&xT[k][tr * 8 + 4];
      *(float4*)&wvv[0] = *(const float4*)&Ws[k][tc * 8];
      *(float4*)&wvv[4] = *(const float4*)&Ws[k][tc * 8 + 4];
#pragma unroll
      for (int ii = 0; ii < 8; ++ii)
#pragma unroll
        for (int jj = 0; jj < 8; ++jj)
          acc[ii][jj] = fmaf(xv[ii], wvv[jj], acc[ii][jj]);
    }
  }

#pragma unroll
  for (int ii = 0; ii < 8; ++ii) {
    int rr = row0 + tr * 8 + ii;
    if (rr < M) {
      float s = dinv[rr];
      uint4 o;
      o.x = (unsigned int)f2bf(acc[ii][0] * s) | ((unsigned int)f2bf(acc[ii][1] * s) << 16);
      o.y = (unsigned int)f2bf(acc[ii][2] * s) | ((unsigned int)f2bf(acc[ii][3] * s) << 16);
      o.z = (unsigned int)f2bf(acc[ii][4] * s) | ((unsigned int)f2bf(acc[ii][5] * s) << 16);
      o.w = (unsigned int)f2bf(acc[ii][6] * s) | ((unsigned int)f2bf(acc[ii][7] * s) << 16);
      *(uint4*)(gb + (size_t)rr * OUT_DIM + tc * 8) = o;
    }
  }
}

// ------------------------------------------------------------------ pull aggregation over [rs_start, cur_end) slabs (full-width —
// r11 falsified column-split: fabric is partially transaction-limited).
__global__ __launch_bounds__(256) void k_agg_se(const unsigned short* __restrict__ gb,
                                                const int* __restrict__ rs_start, const int* __restrict__ cur_end,
                                                const int* __restrict__ csr, const float* __restrict__ dinv,
                                                const float* __restrict__ bias, float* __restrict__ out, int n) {
  const int lane = threadIdx.x & 63;
  const int wave = __builtin_amdgcn_readfirstlane(threadIdx.x >> 6);
  const int wpb = blockDim.x >> 6;
  const int nWaves = gridDim.x * wpb;
  const int c2 = lane * 2;
  const float2 bb = *(const float2*)(bias + c2);

  for (int node = blockIdx.x * wpb + wave; node < n; node += nWaves) {
    const int s = rs_start[node];
    const int e = cur_end[node];
    unsigned int sv = *(const unsigned int*)(gb + (size_t)node * OUT_DIM + c2);
    float ax = bf_lo(sv), ay = bf_hi(sv);
    int i = s;
    for (; i + 8 <= e; i += 8) {
      int s0 = csr[i + 0], s1 = csr[i + 1], s2 = csr[i + 2], s3 = csr[i + 3];
      int s4 = csr[i + 4], s5 = csr[i + 5], s6 = csr[i + 6], s7 = csr[i + 7];
      unsigned int v0 = *(const unsigned int*)(gb + (size_t)s0 * OUT_DIM + c2);
      unsigned int v1 = *(const unsigned int*)(gb + (size_t)s1 * OUT_DIM + c2);
      unsigned int v2 = *(const unsigned int*)(gb + (size_t)s2 * OUT_DIM + c2);
      unsigned int v3 = *(const unsigned int*)(gb + (size_t)s3 * OUT_DIM + c2);
      unsigned int v4 = *(const unsigned int*)(gb + (size_t)s4 * OUT_DIM + c2);
      unsigned int v5 = *(const unsigned int*)(gb + (size_t)s5 * OUT_DIM + c2);
      unsigned int v6 = *(const unsigned int*)(gb + (size_t)s6 * OUT_DIM + c2);
      unsigned int v7 = *(const unsigned int*)(gb + (size_t)s7 * OUT_DIM + c2);
      ax += ((bf_lo(v0) + bf_lo(v1)) + (bf_lo(v2) + bf_lo(v3))) +
            ((bf_lo(v4) + bf_lo(v5)) + (bf_lo(v6) + bf_lo(v7)));
      ay += ((bf_hi(v0) + bf_hi(v1)) + (bf_hi(v2) + bf_hi(v3))) +
            ((bf_hi(v4) + bf_hi(v5)) + (bf_hi(v6) + bf_hi(v7)));
    }
    for (; i < e; ++i) {
      unsigned int v = *(const unsigned int*)(gb + (size_t)csr[i] * OUT_DIM + c2);
      ax += bf_lo(v);
      ay += bf_hi(v);
    }
    const float di = dinv[node];
    vfloat2 o;
    o.x = fmaxf(fmaf(ax, di, bb.x), 0.0f);
    o.y = fmaxf(fmaf(ay, di, bb.y), 0.0f);
    __builtin_nontemporal_store(o, (vfloat2*)(out + (size_t)node * OUT_DIM + c2));
  }
}

// ------------------------------------------------------------------ fallback (small ws): atomic scatter
__global__ __launch_bounds__(256) void k_scatter(const int* __restrict__ ei, int E,
                                                 const unsigned short* __restrict__ gb, float* __restrict__ out) {
  const int lane = threadIdx.x & 63;
  const int wave = __builtin_amdgcn_readfirstlane(threadIdx.x >> 6);
  const int wpb = blockDim.x >> 6;
  const int nWaves = gridDim.x * wpb;
  const int c2 = lane * 2;
  for (int e = blockIdx.x * wpb + wave; e < E; e += nWaves) {
    int s = ei[e];
    int d = ei[E + e];
    unsigned int v = *(const unsigned int*)(gb + (size_t)s * OUT_DIM + c2);
    atomicAdd(&out[(size_t)d * OUT_DIM + c2 + 0], bf_lo(v));
    atomicAdd(&out[(size_t)d * OUT_DIM + c2 + 1], bf_hi(v));
  }
}

__global__ void k_finalize(const unsigned short* __restrict__ gb, const float* __restrict__ dinv,
                           const float* __restrict__ bias, float* __restrict__ out, int n) {
  int i = blockIdx.x * blockDim.x + threadIdx.x;
  int st = gridDim.x * blockDim.x;
  int total = n * OUT_DIM;
  for (; i < total; i += st) {
    int node = i >> 7;
    float gv = __uint_as_float(((unsigned int)gb[i]) << 16);
    float v = (out[i] + gv) * dinv[node] + bias[i & 127];
    out[i] = fmaxf(v, 0.0f);
  }
}

// ------------------------------------------------------------------ launch
extern "C" void kernel_launch(void* const* d_in, const int* in_sizes, int n_in,
                              void* d_out, int out_size, void* d_ws, size_t ws_size,
                              hipStream_t stream) {
  const float* x = (const float*)d_in[0];
  const int* ei = (const int*)d_in[1];   // int64 in reference -> delivered as int32
  const float* W = (const float*)d_in[2];
  const float* bias = (const float*)d_in[3];
  float* out = (float*)d_out;

  const int N = in_sizes[0] / IN_DIM;  // 100000
  const int E = in_sizes[1] / 2;       // 1600000

  const int rs = (N + NR - 1) / NR;
  const int nsub = (rs + NS - 1) / NS;         // 49
  const int nBlocksB = nsub * NR;              // 392
  const int csr_total = nBlocksB * SCAP;
  const int bcap = E / NR + E / 64 + 256;
  const int mBlocks64 = (N + 63) / 64;

  char* ws = (char*)d_ws;
  size_t off = 0;
  auto alloc = [&](size_t bytes) -> void* {
    void* p = ws + off;
    off += (bytes + 255) & ~(size_t)255;
    return p;
  };

  unsigned short* gb = (unsigned short*)alloc((size_t)N * OUT_DIM * sizeof(unsigned short));  // 25.6 MB
  float* dinv = (float*)alloc((size_t)N * sizeof(float));
  int* rs_start = (int*)alloc((size_t)N * sizeof(int));
  int* cur_end = (int*)alloc((size_t)N * sizeof(int));
  int* csr = (int*)alloc((size_t)csr_total * sizeof(int));                                    // 7.6 MB
  unsigned int* bkt = (unsigned int*)alloc((size_t)NR * bcap * sizeof(unsigned int));         // 7.2 MB
  unsigned int* sbkt = (unsigned int*)alloc((size_t)nBlocksB * SBCAP * sizeof(unsigned int)); // 7.6 MB
  int* sbcnt = (int*)alloc((size_t)nBlocksB * sizeof(int));
  unsigned short* Wt_g = (unsigned short*)alloc((size_t)IN_DIM * OUT_DIM * sizeof(unsigned short));  // 32 KB
  int* bmeta = (int*)alloc(16 * sizeof(int));
  int2* ovf = (int2*)alloc((size_t)(E / 8 + 1024) * sizeof(int2));                            // 1.6 MB
  size_t bucket_need = off;

  const bool bucketed = (ws_size >= bucket_need) && (N <= (1 << 17)) && (rs <= (1 << 14)) &&
                        (nsub <= NSUB_MAX);

  if (bucketed) {
    k_init<<<64, 256, 0, stream>>>(bmeta, sbcnt, nBlocksB, W, Wt_g);
    int aGrid = ((E >> 2) + 511) >> 9;
    if (aGrid < 1) aGrid = 1;
    k_bucket2<<<aGrid, 256, 0, stream>>>(ei, E, N, bkt, bcap, bmeta, ovf, bmeta + 8);
    k_subbkt<<<nBlocksB, 256, 0, stream>>>(bkt, bcap, bmeta, sbkt, sbcnt, nsub, N, ovf, bmeta + 8);
    k_subsort2<<<nBlocksB, 256, 0, stream>>>(sbkt, sbcnt, N, csr, rs_start, cur_end, dinv,
                                             ovf, bmeta + 8);
    k_gemm_mfma<<<mBlocks64, 256, 0, stream>>>(x, Wt_g, dinv, gb, N);
    k_agg_se<<<2048, 256, 0, stream>>>(gb, rs_start, cur_end, csr, dinv, bias, out, N);
  } else {
    off = 0;
    unsigned short* gb2 = (unsigned short*)alloc((size_t)N * OUT_DIM * sizeof(unsigned short));
    int* deg = (int*)alloc((size_t)N * sizeof(int));
    float* dinv2 = (float*)alloc((size_t)N * sizeof(float));
    if (ws_size < off) return;
    k_zero_i32<<<256, 256, 0, stream>>>(deg, N);
    k_hist<<<2048, 256, 0, stream>>>(ei + E, E, deg);
    k_dinv<<<512, 256, 0, stream>>>(deg, dinv2, N);
    k_gemm_scale<<<(N + 127) / 128, 256, 0, stream>>>(x, W, dinv2, gb2, N);
    k_zero_f32<<<2048, 256, 0, stream>>>(out, (long long)N * OUT_DIM);
    k_scatter<<<4096, 256, 0, stream>>>(ei, E, gb2, out);
    k_finalize<<<2048, 256, 0, stream>>>(gb2, dinv2, bias, out, N);
  }
}